// Round 11
// baseline (158.050 us; speedup 1.0000x reference)
//
#include <hip/hip_runtime.h>

// KGAT 3-layer forward. Inputs (all f32/int32, setup_inputs order):
// 0 embed[N,64], 1 w1_0[64,64], 2 b1_0, 3 w2_0, 4 b2_0,
// 5 w1_1[32,64], 6 b1_1, 7 w2_1, 8 b2_1, 9 w1_2[16,32], 10 b1_2, 11 w2_2, 12 b2_2,
// 13 edge_val[E], 14 edge_row[E], 15 edge_col[E]
// Output f32 [N,176] = [embed | l2n(ego1) | l2n(ego2) | l2n(ego3)]

#define NODES 100000
#define OUT_STRIDE 176

typedef _Float16 f16x8 __attribute__((ext_vector_type(8)));
typedef float f32x4 __attribute__((ext_vector_type(4)));
typedef _Float16 half4_t __attribute__((ext_vector_type(4)));
typedef unsigned long long u64;

static constexpr int NV = NODES + 1;
static constexpr int NB = 256;                      // blocks for count/scatter
static constexpr int BINH = (NODES + 255) / 256;    // 391 coarse buckets (row>>8)
static constexpr int M_SCAN = BINH * NB;            // 100096
static constexpr int NC1 = (M_SCAN + 1023) / 1024;  // 98 scan chunks
static constexpr int CAP = 4096;                    // max edges/bucket (mean ~3070)

// ---------------- CSR build: bucket sort, LDS-only atomics (proven r8) ----------------

__global__ __launch_bounds__(1024) void bucket_count_kernel(const int* __restrict__ rows,
                                                            int* __restrict__ gh,
                                                            int e, int chunk) {
    __shared__ int lh[BINH];
    for (int t = threadIdx.x; t < BINH; t += 1024) lh[t] = 0;
    __syncthreads();
    int b = blockIdx.x;
    int start = b * chunk, end = min(e, start + chunk);
    for (int i = start + threadIdx.x; i < end; i += 1024)
        atomicAdd(&lh[rows[i] >> 8], 1);
    __syncthreads();
    for (int t = threadIdx.x; t < BINH; t += 1024) gh[t * NB + b] = lh[t];  // bin-major
}

__global__ __launch_bounds__(1024) void scan_k1(const int* __restrict__ in, int* __restrict__ out,
                                                int* __restrict__ sums, int m) {
    int i = blockIdx.x * 1024 + threadIdx.x;
    int v = (i < m) ? in[i] : 0;
    int lane = threadIdx.x & 63, wid = threadIdx.x >> 6;
    int incl = v;
    #pragma unroll
    for (int off = 1; off < 64; off <<= 1) {
        int t = __shfl_up(incl, off);
        if (lane >= off) incl += t;
    }
    __shared__ int wsum[16];
    if (lane == 63) wsum[wid] = incl;
    __syncthreads();
    int woff = 0;
    for (int k = 0; k < wid; ++k) woff += wsum[k];
    if (i < m) out[i] = incl - v + woff;
    if (threadIdx.x == 1023) sums[blockIdx.x] = incl + woff;  // block total
}

__global__ __launch_bounds__(1024) void scan_k2(int* __restrict__ sums, int nc) {
    int t = threadIdx.x;
    int v = (t < nc) ? sums[t] : 0;
    int lane = t & 63, wid = t >> 6;
    int incl = v;
    #pragma unroll
    for (int off = 1; off < 64; off <<= 1) {
        int x = __shfl_up(incl, off);
        if (lane >= off) incl += x;
    }
    __shared__ int wsum[16];
    if (lane == 63) wsum[wid] = incl;
    __syncthreads();
    int woff = 0;
    for (int k = 0; k < wid; ++k) woff += wsum[k];
    if (t < nc) sums[t] = incl - v + woff;  // exclusive
}

__global__ __launch_bounds__(1024) void scan_k3(int* __restrict__ out, const int* __restrict__ sums,
                                                int m) {
    int i = blockIdx.x * 1024 + threadIdx.x;
    if (i < m) out[i] += sums[blockIdx.x];
}

__global__ __launch_bounds__(1024) void bucket_scatter_kernel(
    const int* __restrict__ rows, const int* __restrict__ cols, const float* __restrict__ vals,
    const int* __restrict__ ghs, u64* __restrict__ tmp, int e, int chunk) {
    __shared__ int cur[BINH];
    int b = blockIdx.x;
    for (int t = threadIdx.x; t < BINH; t += 1024) cur[t] = ghs[t * NB + b];
    __syncthreads();
    int start = b * chunk, end = min(e, start + chunk);
    for (int i = start + threadIdx.x; i < end; i += 1024) {
        int r = rows[i];
        unsigned v15 = __float2uint_rn(vals[i] * 32767.f);
        unsigned pk = (unsigned)cols[i] | (v15 << 17);
        int pos = atomicAdd(&cur[r >> 8], 1);   // LDS atomic; (blk,bin) ranges disjoint
        tmp[pos] = ((u64)(unsigned)r << 32) | pk;
    }
}

__global__ __launch_bounds__(1024) void bucket_sort_kernel(
    const u64* __restrict__ tmp, const int* __restrict__ ghs,
    unsigned* __restrict__ sorted, int* __restrict__ row_ptr, int e) {
    __shared__ u64 ebuf[CAP];
    __shared__ int hist[256], bstart[256], cursor[256], ws4[4];
    int b = blockIdx.x, t = threadIdx.x;
    int base = ghs[b * NB];
    int endp = (b == BINH - 1) ? e : ghs[(b + 1) * NB];
    int size = min(endp - base, CAP);
    for (int i = t; i < 256; i += 1024) hist[i] = 0;
    __syncthreads();
    for (int i = t; i < size; i += 1024) {
        u64 ev = tmp[base + i];
        ebuf[i] = ev;
        atomicAdd(&hist[(int)(ev >> 32) & 255], 1);
    }
    __syncthreads();
    {
        int v = (t < 256) ? hist[t] : 0;
        int lane = t & 63, wid = t >> 6;
        int incl = v;
        #pragma unroll
        for (int off = 1; off < 64; off <<= 1) {
            int x = __shfl_up(incl, off);
            if (lane >= off) incl += x;
        }
        if (lane == 63 && wid < 4) ws4[wid] = incl;
        __syncthreads();
        if (t < 256) {
            int woff = 0;
            for (int k = 0; k < wid; ++k) woff += ws4[k];
            int ex = incl - v + woff;
            bstart[t] = ex;
            cursor[t] = ex;
            int rr = b * 256 + t;
            if (rr <= NODES) row_ptr[rr] = base + ex;  // covers empties; rr==NODES -> E
        }
    }
    __syncthreads();
    for (int i = t; i < size; i += 1024) {
        u64 ev = ebuf[i];
        int bin = (int)(ev >> 32) & 255;
        int pos = base + atomicAdd(&cursor[bin], 1);
        sorted[pos] = (unsigned)ev;
    }
}

// ------- cols 0..63 = raw embed (f32) + build fp16 copy of embed -------

__global__ void prep_embed_kernel(const float4* __restrict__ x4, float4* __restrict__ out4,
                                  half4_t* __restrict__ xh) {
    int i = blockIdx.x * blockDim.x + threadIdx.x;
    if (i < NODES * 16) {
        int r = i >> 4, c = i & 15;
        float4 v = x4[i];
        out4[r * (OUT_STRIDE / 4) + c] = v;
        xh[i] = half4_t{(_Float16)v.x, (_Float16)v.y, (_Float16)v.z, (_Float16)v.w};
    }
}

// ---------------- fused layer: spmm + MFMA aggregate + l2norm ----------------
// r10 structure (direct A-fragment gather, zero staging LDS) with:
//  - 256-thread blocks (4 waves), up to 8 blocks/CU -> finer drain, 32 waves/CU
//  - nontemporal edge loads + output stores (don't evict x-table from L2)

template <int DIN, int DOUT>
__global__ __launch_bounds__(256, 8) void layer_kernel(
    const _Float16* __restrict__ xh, const unsigned* __restrict__ edges,
    const int* __restrict__ row_ptr,
    const float* __restrict__ w1, const float* __restrict__ b1,
    const float* __restrict__ w2, const float* __restrict__ b2,
    _Float16* __restrict__ ego_out,  // [n, DOUT] fp16 (null for last layer)
    float* __restrict__ outp,        // d_out + column offset, row stride 176
    int n) {
    constexpr int KT = DIN / 32;        // MFMA K-tiles == f16x8 chunks per lane
    constexpr int NT = DOUT / 16;       // MFMA N-tiles
    constexpr int NFRAG = 2 * KT * NT;  // weight fragments (w1 + w2)

    __shared__ f16x8 wfrag[NFRAG * 64];

    for (int slot = threadIdx.x; slot < NFRAG * 64; slot += 256) {
        int l = slot & 63, fid = slot >> 6;
        int mat = fid / (KT * NT);
        int kt = (fid / NT) % KT;
        int nt = fid % NT;
        const float* w = mat ? w2 : w1;
        int o = nt * 16 + (l & 15);
        int kb = kt * 32 + (l >> 4) * 8;
        const float* src = w + o * DIN + kb;
        f16x8 f;
        #pragma unroll
        for (int jj = 0; jj < 8; ++jj) f[jj] = (_Float16)src[jj];
        wfrag[slot] = f;
    }
    __syncthreads();

    int wid = threadIdx.x >> 6, lane = threadIdx.x & 63;
    int q = lane >> 4, cl = lane & 15;

    int r0 = blockIdx.x * 64 + wid * 16;   // wave's 16-row tile
    int r = r0 + cl;                       // lane's graph row (A-row = cl)
    bool valid = r < n;
    int rr = valid ? r : 0;
    int s = valid ? row_ptr[rr] : 0;
    int e = valid ? row_ptr[rr + 1] : 0;

    f16x8 accv[KT];
    #pragma unroll
    for (int ck = 0; ck < KT; ++ck) accv[ck] = (f16x8)(_Float16)0;

    constexpr float SCL = 1.f / 32767.f;
    const _Float16* xq = xh + q * 8;   // lane's k-chunk offset within any row
    int j = s;
    for (; j + 3 < e; j += 4) {
        unsigned pk[4];
        #pragma unroll
        for (int k = 0; k < 4; ++k) pk[k] = __builtin_nontemporal_load(&edges[j + k]);
        #pragma unroll
        for (int k = 0; k < 4; ++k) {
            const _Float16* p = xq + (size_t)(pk[k] & 0x1FFFFu) * DIN;
            _Float16 vh = (_Float16)((float)(pk[k] >> 17) * SCL);
            #pragma unroll
            for (int ck = 0; ck < KT; ++ck)
                accv[ck] += (*(const f16x8*)(p + ck * 32)) * vh;  // v_pk_fma_f16
        }
    }
    for (; j < e; ++j) {
        unsigned p = __builtin_nontemporal_load(&edges[j]);
        _Float16 vh = (_Float16)((float)(p >> 17) * SCL);
        const _Float16* xp = xq + (size_t)(p & 0x1FFFFu) * DIN;
        #pragma unroll
        for (int ck = 0; ck < KT; ++ck)
            accv[ck] += (*(const f16x8*)(xp + ck * 32)) * vh;
    }

    // ego in the same fragment layout; sum/bi in-register (no LDS round-trip)
    f16x8 sumA[KT], biA[KT];
    {
        const _Float16* er = xq + (size_t)rr * DIN;
        #pragma unroll
        for (int ck = 0; ck < KT; ++ck) {
            f16x8 eg = *(const f16x8*)(er + ck * 32);
            sumA[ck] = eg + accv[ck];
            biA[ck]  = eg * accv[ck];
        }
    }

    float bias1[NT], bias2[NT];
    #pragma unroll
    for (int nt = 0; nt < NT; ++nt) {
        bias1[nt] = b1[nt * 16 + cl];
        bias2[nt] = b2[nt * 16 + cl];
    }

    float ov[NT][4];
    #pragma unroll
    for (int nt = 0; nt < NT; ++nt) {
        f32x4 c1 = {bias1[nt], bias1[nt], bias1[nt], bias1[nt]};
        f32x4 c2 = {bias2[nt], bias2[nt], bias2[nt], bias2[nt]};
        #pragma unroll
        for (int kt = 0; kt < KT; ++kt) {
            f16x8 wa = wfrag[((0 * KT + kt) * NT + nt) * 64 + lane];
            f16x8 wb = wfrag[((1 * KT + kt) * NT + nt) * 64 + lane];
            c1 = __builtin_amdgcn_mfma_f32_16x16x32_f16(sumA[kt], wa, c1, 0, 0, 0);
            c2 = __builtin_amdgcn_mfma_f32_16x16x32_f16(biA[kt], wb, c2, 0, 0, 0);
        }
        #pragma unroll
        for (int t = 0; t < 4; ++t) {
            float u1 = c1[t] > 0.f ? c1[t] : 0.01f * c1[t];
            float u2 = c2[t] > 0.f ? c2[t] : 0.01f * c2[t];
            ov[nt][t] = u1 + u2;
        }
    }

    // ---- l2norm + stores: row = r0 + 4q + t, col = nt*16 + cl ----
    #pragma unroll
    for (int t = 0; t < 4; ++t) {
        float sq = 0.f;
        #pragma unroll
        for (int nt = 0; nt < NT; ++nt) sq += ov[nt][t] * ov[nt][t];
        #pragma unroll
        for (int off = 1; off < 16; off <<= 1) sq += __shfl_xor(sq, off);
        float inv = 1.f / fmaxf(sqrtf(sq), 1e-12f);
        int rw = r0 + 4 * q + t;
        if (rw < n) {
            #pragma unroll
            for (int nt = 0; nt < NT; ++nt) {
                float o = ov[nt][t];
                if (ego_out)
                    __builtin_nontemporal_store((_Float16)o,
                        &ego_out[(size_t)rw * DOUT + nt * 16 + cl]);
                __builtin_nontemporal_store(o * inv,
                    &outp[(size_t)rw * OUT_STRIDE + nt * 16 + cl]);
            }
        }
    }
}

// ---------------- launch ----------------

static size_t align_up(size_t x) { return (x + 255) & ~(size_t)255; }

extern "C" void kernel_launch(void* const* d_in, const int* in_sizes, int n_in,
                              void* d_out, int out_size, void* d_ws, size_t ws_size,
                              hipStream_t stream) {
    const float* embed = (const float*)d_in[0];
    const float* w1_0 = (const float*)d_in[1];  const float* b1_0 = (const float*)d_in[2];
    const float* w2_0 = (const float*)d_in[3];  const float* b2_0 = (const float*)d_in[4];
    const float* w1_1 = (const float*)d_in[5];  const float* b1_1 = (const float*)d_in[6];
    const float* w2_1 = (const float*)d_in[7];  const float* b2_1 = (const float*)d_in[8];
    const float* w1_2 = (const float*)d_in[9];  const float* b1_2 = (const float*)d_in[10];
    const float* w2_2 = (const float*)d_in[11]; const float* b2_2 = (const float*)d_in[12];
    const float* edge_val = (const float*)d_in[13];
    const int*   edge_row = (const int*)d_in[14];
    const int*   edge_col = (const int*)d_in[15];
    const int E = in_sizes[14];
    const int N = in_sizes[0] / 64;
    float* out = (float*)d_out;

    // workspace carve-up (~48 MB)
    char* ws = (char*)d_ws;
    size_t off = 0;
    int* row_ptr   = (int*)(ws + off); off = align_up(off + (size_t)NV * 4);
    int* gh        = (int*)(ws + off); off = align_up(off + (size_t)M_SCAN * 4);
    int* ghs       = (int*)(ws + off); off = align_up(off + (size_t)M_SCAN * 4);
    int* sums      = (int*)(ws + off); off = align_up(off + (size_t)256 * 4);
    u64* tmp       = (u64*)(ws + off); off = align_up(off + (size_t)E * 8);
    unsigned* sorted = (unsigned*)(ws + off); off = align_up(off + (size_t)E * 4);
    _Float16* embed_h = (_Float16*)(ws + off); off = align_up(off + (size_t)N * 64 * 2);
    _Float16* ego1_h  = (_Float16*)(ws + off); off = align_up(off + (size_t)N * 64 * 2);
    _Float16* ego2_h  = (_Float16*)(ws + off); off = align_up(off + (size_t)N * 32 * 2);
    (void)ws_size; (void)n_in; (void)out_size;

    int chunk = (E + NB - 1) / NB;
    bucket_count_kernel<<<NB, 1024, 0, stream>>>(edge_row, gh, E, chunk);
    scan_k1<<<NC1, 1024, 0, stream>>>(gh, ghs, sums, M_SCAN);
    scan_k2<<<1, 1024, 0, stream>>>(sums, NC1);
    scan_k3<<<NC1, 1024, 0, stream>>>(ghs, sums, M_SCAN);
    bucket_scatter_kernel<<<NB, 1024, 0, stream>>>(edge_row, edge_col, edge_val, ghs, tmp, E, chunk);
    bucket_sort_kernel<<<BINH, 1024, 0, stream>>>(tmp, ghs, sorted, row_ptr, E);

    prep_embed_kernel<<<(N * 16 + 255) / 256, 256, 0, stream>>>(
        (const float4*)embed, (float4*)out, (half4_t*)embed_h);

    int lb = (N + 63) / 64;  // 4 waves/block, 16 rows/wave
    layer_kernel<64, 64><<<lb, 256, 0, stream>>>(embed_h, sorted, row_ptr,
        w1_0, b1_0, w2_0, b2_0, ego1_h, out + 64, N);
    layer_kernel<64, 32><<<lb, 256, 0, stream>>>(ego1_h, sorted, row_ptr,
        w1_1, b1_1, w2_1, b2_1, ego2_h, out + 128, N);
    layer_kernel<32, 16><<<lb, 256, 0, stream>>>(ego2_h, sorted, row_ptr,
        w1_2, b1_2, w2_2, b2_2, nullptr, out + 160, N);
}

// Round 12
// 144.763 us; speedup vs baseline: 1.0918x; 1.0918x over previous
//
#include <hip/hip_runtime.h>

// KGAT 3-layer forward. Inputs (all f32/int32, setup_inputs order):
// 0 embed[N,64], 1 w1_0[64,64], 2 b1_0, 3 w2_0, 4 b2_0,
// 5 w1_1[32,64], 6 b1_1, 7 w2_1, 8 b2_1, 9 w1_2[16,32], 10 b1_2, 11 w2_2, 12 b2_2,
// 13 edge_val[E], 14 edge_row[E], 15 edge_col[E]
// Output f32 [N,176] = [embed | l2n(ego1) | l2n(ego2) | l2n(ego3)]

#define NODES 100000
#define OUT_STRIDE 176

typedef _Float16 f16x8 __attribute__((ext_vector_type(8)));
typedef float f32x4 __attribute__((ext_vector_type(4)));
typedef _Float16 half4_t __attribute__((ext_vector_type(4)));
typedef unsigned long long u64;

static constexpr int NV = NODES + 1;
static constexpr int NB = 256;                      // blocks for count/scatter
static constexpr int BINH = (NODES + 255) / 256;    // 391 coarse buckets (row>>8)
static constexpr int M_SCAN = BINH * NB;            // 100096
static constexpr int NC1 = (M_SCAN + 1023) / 1024;  // 98 scan chunks
static constexpr int CAP = 4096;                    // max edges/bucket (mean ~3070)

// ---------------- CSR build: bucket sort, LDS-only atomics (proven r8) ----------------

__global__ __launch_bounds__(1024) void bucket_count_kernel(const int* __restrict__ rows,
                                                            int* __restrict__ gh,
                                                            int e, int chunk) {
    __shared__ int lh[BINH];
    for (int t = threadIdx.x; t < BINH; t += 1024) lh[t] = 0;
    __syncthreads();
    int b = blockIdx.x;
    int start = b * chunk, end = min(e, start + chunk);
    for (int i = start + threadIdx.x; i < end; i += 1024)
        atomicAdd(&lh[rows[i] >> 8], 1);
    __syncthreads();
    for (int t = threadIdx.x; t < BINH; t += 1024) gh[t * NB + b] = lh[t];  // bin-major
}

__global__ __launch_bounds__(1024) void scan_k1(const int* __restrict__ in, int* __restrict__ out,
                                                int* __restrict__ sums, int m) {
    int i = blockIdx.x * 1024 + threadIdx.x;
    int v = (i < m) ? in[i] : 0;
    int lane = threadIdx.x & 63, wid = threadIdx.x >> 6;
    int incl = v;
    #pragma unroll
    for (int off = 1; off < 64; off <<= 1) {
        int t = __shfl_up(incl, off);
        if (lane >= off) incl += t;
    }
    __shared__ int wsum[16];
    if (lane == 63) wsum[wid] = incl;
    __syncthreads();
    int woff = 0;
    for (int k = 0; k < wid; ++k) woff += wsum[k];
    if (i < m) out[i] = incl - v + woff;
    if (threadIdx.x == 1023) sums[blockIdx.x] = incl + woff;  // block total
}

__global__ __launch_bounds__(1024) void scan_k2(int* __restrict__ sums, int nc) {
    int t = threadIdx.x;
    int v = (t < nc) ? sums[t] : 0;
    int lane = t & 63, wid = t >> 6;
    int incl = v;
    #pragma unroll
    for (int off = 1; off < 64; off <<= 1) {
        int x = __shfl_up(incl, off);
        if (lane >= off) incl += x;
    }
    __shared__ int wsum[16];
    if (lane == 63) wsum[wid] = incl;
    __syncthreads();
    int woff = 0;
    for (int k = 0; k < wid; ++k) woff += wsum[k];
    if (t < nc) sums[t] = incl - v + woff;  // exclusive
}

__global__ __launch_bounds__(1024) void scan_k3(int* __restrict__ out, const int* __restrict__ sums,
                                                int m) {
    int i = blockIdx.x * 1024 + threadIdx.x;
    if (i < m) out[i] += sums[blockIdx.x];
}

__global__ __launch_bounds__(1024) void bucket_scatter_kernel(
    const int* __restrict__ rows, const int* __restrict__ cols, const float* __restrict__ vals,
    const int* __restrict__ ghs, u64* __restrict__ tmp, int e, int chunk) {
    __shared__ int cur[BINH];
    int b = blockIdx.x;
    for (int t = threadIdx.x; t < BINH; t += 1024) cur[t] = ghs[t * NB + b];
    __syncthreads();
    int start = b * chunk, end = min(e, start + chunk);
    for (int i = start + threadIdx.x; i < end; i += 1024) {
        int r = rows[i];
        unsigned v15 = __float2uint_rn(vals[i] * 32767.f);
        unsigned pk = (unsigned)cols[i] | (v15 << 17);
        int pos = atomicAdd(&cur[r >> 8], 1);   // LDS atomic; (blk,bin) ranges disjoint
        tmp[pos] = ((u64)(unsigned)r << 32) | pk;
    }
}

// per-bucket LDS counting sort by row&255 + row_ptr emission + DEGREE-SORTED
// perm within the bucket (descending degree; waves then see near-equal rows).
__global__ __launch_bounds__(1024) void bucket_sort_kernel(
    const u64* __restrict__ tmp, const int* __restrict__ ghs,
    unsigned* __restrict__ sorted, int* __restrict__ row_ptr,
    int* __restrict__ perm, int e) {
    __shared__ u64 ebuf[CAP];
    __shared__ int hist[256], cursor[256], ws4[4];
    __shared__ int dh[64];
    int b = blockIdx.x, t = threadIdx.x;
    int base = ghs[b * NB];
    int endp = (b == BINH - 1) ? e : ghs[(b + 1) * NB];
    int size = min(endp - base, CAP);
    int nvalid = min(256, NODES - b * 256);  // rows in this bucket
    for (int i = t; i < 256; i += 1024) hist[i] = 0;
    if (t < 64) dh[t] = 0;
    __syncthreads();
    for (int i = t; i < size; i += 1024) {
        u64 ev = tmp[base + i];
        ebuf[i] = ev;
        atomicAdd(&hist[(int)(ev >> 32) & 255], 1);
    }
    __syncthreads();
    {
        int v = (t < 256) ? hist[t] : 0;
        int lane = t & 63, wid = t >> 6;
        int incl = v;
        #pragma unroll
        for (int off = 1; off < 64; off <<= 1) {
            int x = __shfl_up(incl, off);
            if (lane >= off) incl += x;
        }
        if (lane == 63 && wid < 4) ws4[wid] = incl;
        __syncthreads();
        if (t < 256) {
            int woff = 0;
            for (int k = 0; k < wid; ++k) woff += ws4[k];
            int ex = incl - v + woff;
            cursor[t] = ex;
            int rr = b * 256 + t;
            if (rr <= NODES) row_ptr[rr] = base + ex;  // covers empties; rr==NODES -> E
        }
    }
    // degree histogram (clamped to 63) over the bucket's valid rows
    int deg = 0;
    if (t < nvalid) {
        deg = min(hist[t], 63);
        atomicAdd(&dh[deg], 1);
    }
    __syncthreads();
    if (t == 0) {  // descending-degree exclusive bases
        int run = 0;
        for (int d = 63; d >= 0; --d) { int x = dh[d]; dh[d] = run; run += x; }
    }
    __syncthreads();
    if (t < nvalid) {
        int pos = atomicAdd(&dh[deg], 1);
        perm[b * 256 + pos] = b * 256 + t;
    }
    __syncthreads();
    for (int i = t; i < size; i += 1024) {
        u64 ev = ebuf[i];
        int bin = (int)(ev >> 32) & 255;
        int pos = base + atomicAdd(&cursor[bin], 1);
        sorted[pos] = (unsigned)ev;
    }
}

// ------- cols 0..63 = raw embed (f32) + build fp16 copy of embed -------

__global__ void prep_embed_kernel(const float4* __restrict__ x4, float4* __restrict__ out4,
                                  half4_t* __restrict__ xh) {
    int i = blockIdx.x * blockDim.x + threadIdx.x;
    if (i < NODES * 16) {
        int r = i >> 4, c = i & 15;
        float4 v = x4[i];
        out4[r * (OUT_STRIDE / 4) + c] = v;
        xh[i] = half4_t{(_Float16)v.x, (_Float16)v.y, (_Float16)v.z, (_Float16)v.w};
    }
}

// ---------------- fused layer: spmm + MFMA aggregate + l2norm ----------------
// Round-9 structure (proven fastest: 512-thr, LDS tiles, packed-fp16 gather)
// + degree-equalized waves: tile slot -> row via perm[] (sorted within each
// 256-row bucket, so a wave's 16 rows have near-equal degree; all accesses
// stay in a 176KB L2-resident window).

template <int DIN, int DOUT>
__global__ __launch_bounds__(512, 6) void layer_kernel(
    const _Float16* __restrict__ xh, const unsigned* __restrict__ edges,
    const int* __restrict__ row_ptr, const int* __restrict__ perm,
    const float* __restrict__ w1, const float* __restrict__ b1,
    const float* __restrict__ w2, const float* __restrict__ b2,
    _Float16* __restrict__ ego_out,  // [n, DOUT] fp16 (null for last layer)
    float* __restrict__ outp,        // d_out + column offset, row stride 176
    int n) {
    constexpr int KT = DIN / 32;
    constexpr int NT = DOUT / 16;
    constexpr int NFRAG = 2 * KT * NT;
    constexpr int DPL = DIN / 4;
    constexpr int C8 = DPL / 8;
    constexpr int SROWH = DIN + 8;

    __shared__ f16x8 wfrag[NFRAG * 64];
    __shared__ _Float16 tiles[8][2][16 * SROWH];

    for (int slot = threadIdx.x; slot < NFRAG * 64; slot += 512) {
        int l = slot & 63, fid = slot >> 6;
        int mat = fid / (KT * NT);
        int kt = (fid / NT) % KT;
        int nt = fid % NT;
        const float* w = mat ? w2 : w1;
        int o = nt * 16 + (l & 15);
        int kb = kt * 32 + (l >> 4) * 8;
        const float* src = w + o * DIN + kb;
        f16x8 f;
        #pragma unroll
        for (int jj = 0; jj < 8; ++jj) f[jj] = (_Float16)src[jj];
        wfrag[slot] = f;
    }
    __syncthreads();

    int wid = threadIdx.x >> 6, lane = threadIdx.x & 63;
    int g = lane >> 2, li = lane & 3;   // gather: tile-slot, dim-chunk
    int q = lane >> 4, cl = lane & 15;  // mfma: quarter, col-in-tile

    float bias1[NT], bias2[NT];
    #pragma unroll
    for (int nt = 0; nt < NT; ++nt) {
        bias1[nt] = b1[nt * 16 + cl];
        bias2[nt] = b2[nt * 16 + cl];
    }

    int r0 = blockIdx.x * 128 + wid * 16;  // wave's 16-slot tile

    // ---- gather phase ----
    int slot = r0 + g;
    bool valid = slot < n;
    int r = valid ? perm[slot] : 0;        // actual graph row
    int s = valid ? row_ptr[r] : 0;
    int e = valid ? row_ptr[r + 1] : 0;

    const _Float16* xrow = xh + (size_t)r * DIN + li * DPL;
    f16x8 egoh[C8];
    #pragma unroll
    for (int c = 0; c < C8; ++c) egoh[c] = *(const f16x8*)(xrow + c * 8);

    f16x8 accv[C8];
    #pragma unroll
    for (int c = 0; c < C8; ++c) accv[c] = (f16x8)(_Float16)0;

    constexpr float SCL = 1.f / 32767.f;
    const _Float16* xbase = xh + li * DPL;
    int j = s;
    for (; j + 3 < e; j += 4) {
        unsigned pk[4];
        #pragma unroll
        for (int k = 0; k < 4; ++k) pk[k] = edges[j + k];
        f16x8 xv[4][C8];
        #pragma unroll
        for (int k = 0; k < 4; ++k) {
            const _Float16* p = xbase + (size_t)(pk[k] & 0x1FFFFu) * DIN;
            #pragma unroll
            for (int c = 0; c < C8; ++c) xv[k][c] = *(const f16x8*)(p + c * 8);
        }
        #pragma unroll
        for (int k = 0; k < 4; ++k) {
            _Float16 vh = (_Float16)((float)(pk[k] >> 17) * SCL);
            #pragma unroll
            for (int c = 0; c < C8; ++c)
                accv[c] += xv[k][c] * vh;       // v_pk_fma_f16
        }
    }
    for (; j < e; ++j) {
        unsigned p = edges[j];
        _Float16 vh = (_Float16)((float)(p >> 17) * SCL);
        const _Float16* xp = xbase + (size_t)(p & 0x1FFFFu) * DIN;
        #pragma unroll
        for (int c = 0; c < C8; ++c)
            accv[c] += (*(const f16x8*)(xp + c * 8)) * vh;
    }

    // sum/bi in packed fp16 (wave-private slots, no barrier needed)
    _Float16* srow = &tiles[wid][0][g * SROWH + li * DPL];
    _Float16* brow = &tiles[wid][1][g * SROWH + li * DPL];
    #pragma unroll
    for (int c = 0; c < C8; ++c) {
        *(f16x8*)(srow + c * 8) = egoh[c] + accv[c];
        *(f16x8*)(brow + c * 8) = egoh[c] * accv[c];
    }

    // ---- MFMA phase ----
    f16x8 sumA[KT], biA[KT];
    #pragma unroll
    for (int kt = 0; kt < KT; ++kt) {
        sumA[kt] = *(const f16x8*)&tiles[wid][0][cl * SROWH + kt * 32 + q * 8];
        biA[kt]  = *(const f16x8*)&tiles[wid][1][cl * SROWH + kt * 32 + q * 8];
    }

    float ov[NT][4];
    #pragma unroll
    for (int nt = 0; nt < NT; ++nt) {
        f32x4 c1 = {bias1[nt], bias1[nt], bias1[nt], bias1[nt]};
        f32x4 c2 = {bias2[nt], bias2[nt], bias2[nt], bias2[nt]};
        #pragma unroll
        for (int kt = 0; kt < KT; ++kt) {
            f16x8 wa = wfrag[((0 * KT + kt) * NT + nt) * 64 + lane];
            f16x8 wb = wfrag[((1 * KT + kt) * NT + nt) * 64 + lane];
            c1 = __builtin_amdgcn_mfma_f32_16x16x32_f16(sumA[kt], wa, c1, 0, 0, 0);
            c2 = __builtin_amdgcn_mfma_f32_16x16x32_f16(biA[kt], wb, c2, 0, 0, 0);
        }
        #pragma unroll
        for (int t = 0; t < 4; ++t) {
            float u1 = c1[t] > 0.f ? c1[t] : 0.01f * c1[t];
            float u2 = c2[t] > 0.f ? c2[t] : 0.01f * c2[t];
            ov[nt][t] = u1 + u2;
        }
    }

    // ---- l2norm + stores: tile slot = r0 + 4q + t, row = perm[slot] ----
    #pragma unroll
    for (int t = 0; t < 4; ++t) {
        float sq = 0.f;
        #pragma unroll
        for (int nt = 0; nt < NT; ++nt) sq += ov[nt][t] * ov[nt][t];
        #pragma unroll
        for (int off = 1; off < 16; off <<= 1) sq += __shfl_xor(sq, off);
        float inv = 1.f / fmaxf(sqrtf(sq), 1e-12f);
        int slot_w = r0 + 4 * q + t;
        if (slot_w < n) {
            int rw = perm[slot_w];
            #pragma unroll
            for (int nt = 0; nt < NT; ++nt) {
                float o = ov[nt][t];
                if (ego_out) ego_out[(size_t)rw * DOUT + nt * 16 + cl] = (_Float16)o;
                outp[(size_t)rw * OUT_STRIDE + nt * 16 + cl] = o * inv;
            }
        }
    }
}

// ---------------- launch ----------------

static size_t align_up(size_t x) { return (x + 255) & ~(size_t)255; }

extern "C" void kernel_launch(void* const* d_in, const int* in_sizes, int n_in,
                              void* d_out, int out_size, void* d_ws, size_t ws_size,
                              hipStream_t stream) {
    const float* embed = (const float*)d_in[0];
    const float* w1_0 = (const float*)d_in[1];  const float* b1_0 = (const float*)d_in[2];
    const float* w2_0 = (const float*)d_in[3];  const float* b2_0 = (const float*)d_in[4];
    const float* w1_1 = (const float*)d_in[5];  const float* b1_1 = (const float*)d_in[6];
    const float* w2_1 = (const float*)d_in[7];  const float* b2_1 = (const float*)d_in[8];
    const float* w1_2 = (const float*)d_in[9];  const float* b1_2 = (const float*)d_in[10];
    const float* w2_2 = (const float*)d_in[11]; const float* b2_2 = (const float*)d_in[12];
    const float* edge_val = (const float*)d_in[13];
    const int*   edge_row = (const int*)d_in[14];
    const int*   edge_col = (const int*)d_in[15];
    const int E = in_sizes[14];
    const int N = in_sizes[0] / 64;
    float* out = (float*)d_out;

    // workspace carve-up (~48 MB)
    char* ws = (char*)d_ws;
    size_t off = 0;
    int* row_ptr   = (int*)(ws + off); off = align_up(off + (size_t)NV * 4);
    int* perm      = (int*)(ws + off); off = align_up(off + (size_t)NODES * 4);
    int* gh        = (int*)(ws + off); off = align_up(off + (size_t)M_SCAN * 4);
    int* ghs       = (int*)(ws + off); off = align_up(off + (size_t)M_SCAN * 4);
    int* sums      = (int*)(ws + off); off = align_up(off + (size_t)256 * 4);
    u64* tmp       = (u64*)(ws + off); off = align_up(off + (size_t)E * 8);
    unsigned* sorted = (unsigned*)(ws + off); off = align_up(off + (size_t)E * 4);
    _Float16* embed_h = (_Float16*)(ws + off); off = align_up(off + (size_t)N * 64 * 2);
    _Float16* ego1_h  = (_Float16*)(ws + off); off = align_up(off + (size_t)N * 64 * 2);
    _Float16* ego2_h  = (_Float16*)(ws + off); off = align_up(off + (size_t)N * 32 * 2);
    (void)ws_size; (void)n_in; (void)out_size;

    int chunk = (E + NB - 1) / NB;
    bucket_count_kernel<<<NB, 1024, 0, stream>>>(edge_row, gh, E, chunk);
    scan_k1<<<NC1, 1024, 0, stream>>>(gh, ghs, sums, M_SCAN);
    scan_k2<<<1, 1024, 0, stream>>>(sums, NC1);
    scan_k3<<<NC1, 1024, 0, stream>>>(ghs, sums, M_SCAN);
    bucket_scatter_kernel<<<NB, 1024, 0, stream>>>(edge_row, edge_col, edge_val, ghs, tmp, E, chunk);
    bucket_sort_kernel<<<BINH, 1024, 0, stream>>>(tmp, ghs, sorted, row_ptr, perm, E);

    prep_embed_kernel<<<(N * 16 + 255) / 256, 256, 0, stream>>>(
        (const float4*)embed, (float4*)out, (half4_t*)embed_h);

    int lb = (N + 127) / 128;  // 8 waves/block, 16 rows/wave
    layer_kernel<64, 64><<<lb, 512, 0, stream>>>(embed_h, sorted, row_ptr, perm,
        w1_0, b1_0, w2_0, b2_0, ego1_h, out + 64, N);
    layer_kernel<64, 32><<<lb, 512, 0, stream>>>(ego1_h, sorted, row_ptr, perm,
        w1_1, b1_1, w2_1, b2_1, ego2_h, out + 128, N);
    layer_kernel<32, 16><<<lb, 512, 0, stream>>>(ego2_h, sorted, row_ptr, perm,
        w1_2, b1_2, w2_2, b2_2, nullptr, out + 160, N);
}

// Round 13
// 133.356 us; speedup vs baseline: 1.1852x; 1.0855x over previous
//
#include <hip/hip_runtime.h>

// KGAT 3-layer forward. Inputs (all f32/int32, setup_inputs order):
// 0 embed[N,64], 1 w1_0[64,64], 2 b1_0, 3 w2_0, 4 b2_0,
// 5 w1_1[32,64], 6 b1_1, 7 w2_1, 8 b2_1, 9 w1_2[16,32], 10 b1_2, 11 w2_2, 12 b2_2,
// 13 edge_val[E], 14 edge_row[E], 15 edge_col[E]
// Output f32 [N,176] = [embed | l2n(ego1) | l2n(ego2) | l2n(ego3)]

#define NODES 100000
#define OUT_STRIDE 176

typedef _Float16 f16x8 __attribute__((ext_vector_type(8)));
typedef float f32x4 __attribute__((ext_vector_type(4)));
typedef _Float16 half4_t __attribute__((ext_vector_type(4)));
typedef unsigned long long u64;

static constexpr int NV = NODES + 1;
static constexpr int NB = 256;                      // blocks for count/scatter
static constexpr int BINH = (NODES + 255) / 256;    // 391 coarse buckets (row>>8)
static constexpr int M_SCAN = BINH * NB;            // 100096
static constexpr int NC1 = (M_SCAN + 1023) / 1024;  // 98 scan chunks
static constexpr int CAP = 4096;                    // max edges/bucket (mean ~3070)

// ---------------- CSR build: bucket sort, LDS-only atomics (proven r8) ----------------

__global__ __launch_bounds__(1024) void bucket_count_kernel(const int* __restrict__ rows,
                                                            int* __restrict__ gh,
                                                            int e, int chunk) {
    __shared__ int lh[BINH];
    for (int t = threadIdx.x; t < BINH; t += 1024) lh[t] = 0;
    __syncthreads();
    int b = blockIdx.x;
    int start = b * chunk, end = min(e, start + chunk);
    for (int i = start + threadIdx.x; i < end; i += 1024)
        atomicAdd(&lh[rows[i] >> 8], 1);
    __syncthreads();
    for (int t = threadIdx.x; t < BINH; t += 1024) gh[t * NB + b] = lh[t];  // bin-major
}

__global__ __launch_bounds__(1024) void scan_k1(const int* __restrict__ in, int* __restrict__ out,
                                                int* __restrict__ sums, int m) {
    int i = blockIdx.x * 1024 + threadIdx.x;
    int v = (i < m) ? in[i] : 0;
    int lane = threadIdx.x & 63, wid = threadIdx.x >> 6;
    int incl = v;
    #pragma unroll
    for (int off = 1; off < 64; off <<= 1) {
        int t = __shfl_up(incl, off);
        if (lane >= off) incl += t;
    }
    __shared__ int wsum[16];
    if (lane == 63) wsum[wid] = incl;
    __syncthreads();
    int woff = 0;
    for (int k = 0; k < wid; ++k) woff += wsum[k];
    if (i < m) out[i] = incl - v + woff;
    if (threadIdx.x == 1023) sums[blockIdx.x] = incl + woff;  // block total
}

__global__ __launch_bounds__(1024) void scan_k2(int* __restrict__ sums, int nc) {
    int t = threadIdx.x;
    int v = (t < nc) ? sums[t] : 0;
    int lane = t & 63, wid = t >> 6;
    int incl = v;
    #pragma unroll
    for (int off = 1; off < 64; off <<= 1) {
        int x = __shfl_up(incl, off);
        if (lane >= off) incl += x;
    }
    __shared__ int wsum[16];
    if (lane == 63) wsum[wid] = incl;
    __syncthreads();
    int woff = 0;
    for (int k = 0; k < wid; ++k) woff += wsum[k];
    if (t < nc) sums[t] = incl - v + woff;  // exclusive
}

__global__ __launch_bounds__(1024) void scan_k3(int* __restrict__ out, const int* __restrict__ sums,
                                                int m) {
    int i = blockIdx.x * 1024 + threadIdx.x;
    if (i < m) out[i] += sums[blockIdx.x];
}

__global__ __launch_bounds__(1024) void bucket_scatter_kernel(
    const int* __restrict__ rows, const int* __restrict__ cols, const float* __restrict__ vals,
    const int* __restrict__ ghs, u64* __restrict__ tmp, int e, int chunk) {
    __shared__ int cur[BINH];
    int b = blockIdx.x;
    for (int t = threadIdx.x; t < BINH; t += 1024) cur[t] = ghs[t * NB + b];
    __syncthreads();
    int start = b * chunk, end = min(e, start + chunk);
    for (int i = start + threadIdx.x; i < end; i += 1024) {
        int r = rows[i];
        unsigned v15 = __float2uint_rn(vals[i] * 32767.f);
        unsigned pk = (unsigned)cols[i] | (v15 << 17);
        int pos = atomicAdd(&cur[r >> 8], 1);   // LDS atomic; (blk,bin) ranges disjoint
        tmp[pos] = ((u64)(unsigned)r << 32) | pk;
    }
}

__global__ __launch_bounds__(1024) void bucket_sort_kernel(
    const u64* __restrict__ tmp, const int* __restrict__ ghs,
    unsigned* __restrict__ sorted, int* __restrict__ row_ptr, int e) {
    __shared__ u64 ebuf[CAP];
    __shared__ int hist[256], cursor[256], ws4[4];
    int b = blockIdx.x, t = threadIdx.x;
    int base = ghs[b * NB];
    int endp = (b == BINH - 1) ? e : ghs[(b + 1) * NB];
    int size = min(endp - base, CAP);
    for (int i = t; i < 256; i += 1024) hist[i] = 0;
    __syncthreads();
    for (int i = t; i < size; i += 1024) {
        u64 ev = tmp[base + i];
        ebuf[i] = ev;
        atomicAdd(&hist[(int)(ev >> 32) & 255], 1);
    }
    __syncthreads();
    {
        int v = (t < 256) ? hist[t] : 0;
        int lane = t & 63, wid = t >> 6;
        int incl = v;
        #pragma unroll
        for (int off = 1; off < 64; off <<= 1) {
            int x = __shfl_up(incl, off);
            if (lane >= off) incl += x;
        }
        if (lane == 63 && wid < 4) ws4[wid] = incl;
        __syncthreads();
        if (t < 256) {
            int woff = 0;
            for (int k = 0; k < wid; ++k) woff += ws4[k];
            int ex = incl - v + woff;
            cursor[t] = ex;
            int rr = b * 256 + t;
            if (rr <= NODES) row_ptr[rr] = base + ex;  // covers empties; rr==NODES -> E
        }
    }
    __syncthreads();
    for (int i = t; i < size; i += 1024) {
        u64 ev = ebuf[i];
        int bin = (int)(ev >> 32) & 255;
        int pos = base + atomicAdd(&cursor[bin], 1);
        sorted[pos] = (unsigned)ev;
    }
}

// ------- cols 0..63 = raw embed (f32) + build fp16 copy of embed -------

__global__ void prep_embed_kernel(const float4* __restrict__ x4, float4* __restrict__ out4,
                                  half4_t* __restrict__ xh) {
    int i = blockIdx.x * blockDim.x + threadIdx.x;
    if (i < NODES * 16) {
        int r = i >> 4, c = i & 15;
        float4 v = x4[i];
        out4[r * (OUT_STRIDE / 4) + c] = v;
        xh[i] = half4_t{(_Float16)v.x, (_Float16)v.y, (_Float16)v.z, (_Float16)v.w};
    }
}

// ---------------- fused layer: spmm + MFMA aggregate + l2norm ----------------
// Round-9 structure (proven fastest), ONE change: lane-chunk remap for
// CONTIGUOUS gather segments. Old: lane li read bytes {li*32 + c*16} -- a
// stride-32 pattern spanning the whole 128B row (2 half-utilized 64B
// segments per instr, ~4 requests/edge). New: lane li, chunk c reads bytes
// [c*64 + li*16, +16) -- each instr's 4 sibling lanes cover one contiguous
// fully-utilized 64B segment (2 requests/edge). Tile writes move with the
// load offset, so half-order in the LDS row is preserved.

template <int DIN, int DOUT>
__global__ __launch_bounds__(512, 6) void layer_kernel(
    const _Float16* __restrict__ xh, const unsigned* __restrict__ edges,
    const int* __restrict__ row_ptr,
    const float* __restrict__ w1, const float* __restrict__ b1,
    const float* __restrict__ w2, const float* __restrict__ b2,
    _Float16* __restrict__ ego_out,  // [n, DOUT] fp16 (null for last layer)
    float* __restrict__ outp,        // d_out + column offset, row stride 176
    int n) {
    constexpr int KT = DIN / 32;
    constexpr int NT = DOUT / 16;
    constexpr int NFRAG = 2 * KT * NT;
    constexpr int C8 = DIN / 32;        // f16x8 chunks per lane (DPL/8)
    constexpr int SROWH = DIN + 8;

    __shared__ f16x8 wfrag[NFRAG * 64];
    __shared__ _Float16 tiles[8][2][16 * SROWH];

    for (int slot = threadIdx.x; slot < NFRAG * 64; slot += 512) {
        int l = slot & 63, fid = slot >> 6;
        int mat = fid / (KT * NT);
        int kt = (fid / NT) % KT;
        int nt = fid % NT;
        const float* w = mat ? w2 : w1;
        int o = nt * 16 + (l & 15);
        int kb = kt * 32 + (l >> 4) * 8;
        const float* src = w + o * DIN + kb;
        f16x8 f;
        #pragma unroll
        for (int jj = 0; jj < 8; ++jj) f[jj] = (_Float16)src[jj];
        wfrag[slot] = f;
    }
    __syncthreads();

    int wid = threadIdx.x >> 6, lane = threadIdx.x & 63;
    int g = lane >> 2, li = lane & 3;   // gather: row-in-tile, lane-in-quad
    int q = lane >> 4, cl = lane & 15;  // mfma: quarter, col-in-tile

    float bias1[NT], bias2[NT];
    #pragma unroll
    for (int nt = 0; nt < NT; ++nt) {
        bias1[nt] = b1[nt * 16 + cl];
        bias2[nt] = b2[nt * 16 + cl];
    }

    int r0 = blockIdx.x * 128 + wid * 16;  // wave's 16-row tile

    // ---- gather phase ----
    int r = r0 + g;
    bool valid = r < n;
    int rr = valid ? r : 0;
    int s = valid ? row_ptr[rr] : 0;
    int e = valid ? row_ptr[rr + 1] : 0;

    // lane owns halves (c*4+li)*8 .. +8  (chunk stride 32 halves = 64B)
    const _Float16* xrow = xh + (size_t)rr * DIN + li * 8;
    f16x8 egoh[C8];
    #pragma unroll
    for (int c = 0; c < C8; ++c) egoh[c] = *(const f16x8*)(xrow + c * 32);

    f16x8 accv[C8];
    #pragma unroll
    for (int c = 0; c < C8; ++c) accv[c] = (f16x8)(_Float16)0;

    constexpr float SCL = 1.f / 32767.f;
    const _Float16* xbase = xh + li * 8;
    int j = s;
    for (; j + 3 < e; j += 4) {
        unsigned pk[4];
        #pragma unroll
        for (int k = 0; k < 4; ++k) pk[k] = edges[j + k];
        f16x8 xv[4][C8];
        #pragma unroll
        for (int k = 0; k < 4; ++k) {
            const _Float16* p = xbase + (size_t)(pk[k] & 0x1FFFFu) * DIN;
            #pragma unroll
            for (int c = 0; c < C8; ++c) xv[k][c] = *(const f16x8*)(p + c * 32);
        }
        #pragma unroll
        for (int k = 0; k < 4; ++k) {
            _Float16 vh = (_Float16)((float)(pk[k] >> 17) * SCL);
            #pragma unroll
            for (int c = 0; c < C8; ++c)
                accv[c] += xv[k][c] * vh;       // v_pk_fma_f16
        }
    }
    for (; j < e; ++j) {
        unsigned p = edges[j];
        _Float16 vh = (_Float16)((float)(p >> 17) * SCL);
        const _Float16* xp = xbase + (size_t)(p & 0x1FFFFu) * DIN;
        #pragma unroll
        for (int c = 0; c < C8; ++c)
            accv[c] += (*(const f16x8*)(xp + c * 32)) * vh;
    }

    // sum/bi in packed fp16 (wave-private slots, no barrier needed)
    _Float16* srow = &tiles[wid][0][g * SROWH + li * 8];
    _Float16* brow = &tiles[wid][1][g * SROWH + li * 8];
    #pragma unroll
    for (int c = 0; c < C8; ++c) {
        *(f16x8*)(srow + c * 32) = egoh[c] + accv[c];
        *(f16x8*)(brow + c * 32) = egoh[c] * accv[c];
    }

    // ---- MFMA phase ----
    f16x8 sumA[KT], biA[KT];
    #pragma unroll
    for (int kt = 0; kt < KT; ++kt) {
        sumA[kt] = *(const f16x8*)&tiles[wid][0][cl * SROWH + kt * 32 + q * 8];
        biA[kt]  = *(const f16x8*)&tiles[wid][1][cl * SROWH + kt * 32 + q * 8];
    }

    float ov[NT][4];
    #pragma unroll
    for (int nt = 0; nt < NT; ++nt) {
        f32x4 c1 = {bias1[nt], bias1[nt], bias1[nt], bias1[nt]};
        f32x4 c2 = {bias2[nt], bias2[nt], bias2[nt], bias2[nt]};
        #pragma unroll
        for (int kt = 0; kt < KT; ++kt) {
            f16x8 wa = wfrag[((0 * KT + kt) * NT + nt) * 64 + lane];
            f16x8 wb = wfrag[((1 * KT + kt) * NT + nt) * 64 + lane];
            c1 = __builtin_amdgcn_mfma_f32_16x16x32_f16(sumA[kt], wa, c1, 0, 0, 0);
            c2 = __builtin_amdgcn_mfma_f32_16x16x32_f16(biA[kt], wb, c2, 0, 0, 0);
        }
        #pragma unroll
        for (int t = 0; t < 4; ++t) {
            float u1 = c1[t] > 0.f ? c1[t] : 0.01f * c1[t];
            float u2 = c2[t] > 0.f ? c2[t] : 0.01f * c2[t];
            ov[nt][t] = u1 + u2;
        }
    }

    // ---- l2norm + stores: row = r0 + 4q + t, col = nt*16 + cl ----
    #pragma unroll
    for (int t = 0; t < 4; ++t) {
        float sq = 0.f;
        #pragma unroll
        for (int nt = 0; nt < NT; ++nt) sq += ov[nt][t] * ov[nt][t];
        #pragma unroll
        for (int off = 1; off < 16; off <<= 1) sq += __shfl_xor(sq, off);
        float inv = 1.f / fmaxf(sqrtf(sq), 1e-12f);
        int rw = r0 + 4 * q + t;
        if (rw < n) {
            #pragma unroll
            for (int nt = 0; nt < NT; ++nt) {
                float o = ov[nt][t];
                if (ego_out) ego_out[(size_t)rw * DOUT + nt * 16 + cl] = (_Float16)o;
                outp[(size_t)rw * OUT_STRIDE + nt * 16 + cl] = o * inv;
            }
        }
    }
}

// ---------------- launch ----------------

static size_t align_up(size_t x) { return (x + 255) & ~(size_t)255; }

extern "C" void kernel_launch(void* const* d_in, const int* in_sizes, int n_in,
                              void* d_out, int out_size, void* d_ws, size_t ws_size,
                              hipStream_t stream) {
    const float* embed = (const float*)d_in[0];
    const float* w1_0 = (const float*)d_in[1];  const float* b1_0 = (const float*)d_in[2];
    const float* w2_0 = (const float*)d_in[3];  const float* b2_0 = (const float*)d_in[4];
    const float* w1_1 = (const float*)d_in[5];  const float* b1_1 = (const float*)d_in[6];
    const float* w2_1 = (const float*)d_in[7];  const float* b2_1 = (const float*)d_in[8];
    const float* w1_2 = (const float*)d_in[9];  const float* b1_2 = (const float*)d_in[10];
    const float* w2_2 = (const float*)d_in[11]; const float* b2_2 = (const float*)d_in[12];
    const float* edge_val = (const float*)d_in[13];
    const int*   edge_row = (const int*)d_in[14];
    const int*   edge_col = (const int*)d_in[15];
    const int E = in_sizes[14];
    const int N = in_sizes[0] / 64;
    float* out = (float*)d_out;

    // workspace carve-up (~48 MB)
    char* ws = (char*)d_ws;
    size_t off = 0;
    int* row_ptr   = (int*)(ws + off); off = align_up(off + (size_t)NV * 4);
    int* gh        = (int*)(ws + off); off = align_up(off + (size_t)M_SCAN * 4);
    int* ghs       = (int*)(ws + off); off = align_up(off + (size_t)M_SCAN * 4);
    int* sums      = (int*)(ws + off); off = align_up(off + (size_t)256 * 4);
    u64* tmp       = (u64*)(ws + off); off = align_up(off + (size_t)E * 8);
    unsigned* sorted = (unsigned*)(ws + off); off = align_up(off + (size_t)E * 4);
    _Float16* embed_h = (_Float16*)(ws + off); off = align_up(off + (size_t)N * 64 * 2);
    _Float16* ego1_h  = (_Float16*)(ws + off); off = align_up(off + (size_t)N * 64 * 2);
    _Float16* ego2_h  = (_Float16*)(ws + off); off = align_up(off + (size_t)N * 32 * 2);
    (void)ws_size; (void)n_in; (void)out_size;

    int chunk = (E + NB - 1) / NB;
    bucket_count_kernel<<<NB, 1024, 0, stream>>>(edge_row, gh, E, chunk);
    scan_k1<<<NC1, 1024, 0, stream>>>(gh, ghs, sums, M_SCAN);
    scan_k2<<<1, 1024, 0, stream>>>(sums, NC1);
    scan_k3<<<NC1, 1024, 0, stream>>>(ghs, sums, M_SCAN);
    bucket_scatter_kernel<<<NB, 1024, 0, stream>>>(edge_row, edge_col, edge_val, ghs, tmp, E, chunk);
    bucket_sort_kernel<<<BINH, 1024, 0, stream>>>(tmp, ghs, sorted, row_ptr, E);

    prep_embed_kernel<<<(N * 16 + 255) / 256, 256, 0, stream>>>(
        (const float4*)embed, (float4*)out, (half4_t*)embed_h);

    int lb = (N + 127) / 128;  // 8 waves/block, 16 rows/wave
    layer_kernel<64, 64><<<lb, 512, 0, stream>>>(embed_h, sorted, row_ptr,
        w1_0, b1_0, w2_0, b2_0, ego1_h, out + 64, N);
    layer_kernel<64, 32><<<lb, 512, 0, stream>>>(ego1_h, sorted, row_ptr,
        w1_1, b1_1, w2_1, b2_1, ego2_h, out + 128, N);
    layer_kernel<32, 16><<<lb, 512, 0, stream>>>(ego2_h, sorted, row_ptr,
        w1_2, b1_2, w2_2, b2_2, nullptr, out + 160, N);
}